// Round 6
// baseline (27.494 us; speedup 1.0000x reference)
//
#include <hip/hip_runtime.h>
#include <math.h>

#define KNBR 20
#define BLK  256
#define GRP  32              // lanes per atom
#define APB  (BLK / GRP)     // 8 atoms per block

#define THETA_T  1.9106332362490186f   // 0.6081734479693927 * pi
#define INV_SIG  4.7746482927568605f   // 1 / (12 deg in rad)
#define PI_F     3.14159265358979323846f

// q_l via the SH addition theorem: q_l = (1/nb)*sqrt(cn + 2*sum_{i<j} P_l(d_ij)).
// Pair operands live in REGISTERS (lane s of each 32-lane group holds compacted
// unit vector s); exchange via ds_permute/ds_bpermute — conflict-free LDS
// crossbar, no __shared__ allocation at all.

__device__ __forceinline__ float bperm(int srcLane, float v) {
    return __int_as_float(__builtin_amdgcn_ds_bpermute(srcLane << 2, __float_as_int(v)));
}

__global__ __launch_bounds__(BLK)
void op_kernel(const float* __restrict__ pos,
               const int*   __restrict__ aidx,
               const int*   __restrict__ nidx,
               const int*   __restrict__ vmsk,
               float*       __restrict__ out,
               int M)
{
    const int tid   = threadIdx.x;
    const int r     = tid & (GRP - 1);      // lane within group
    const int g     = tid >> 5;             // group in block 0..7
    const int i     = blockIdx.x * APB + g;
    if (i >= M) return;
    const int lbase = tid & 32;             // group base lane within wave (0/32)

    // center position (uniform within group -> broadcast loads)
    const int a = aidx[i];
    const float cx = pos[3 * a], cy = pos[3 * a + 1], cz = pos[3 * a + 2];

    // lane r < 20 owns neighbor slot r
    int valid = 0, nj = 0;
    if (r < KNBR) {
        nj    = nidx[(size_t)i * KNBR + r];
        valid = vmsk[(size_t)i * KNBR + r] != 0;
    }
    const unsigned long long bal = __ballot(valid != 0);
    const unsigned int b32 = (unsigned int)(bal >> lbase);
    const int total = __popc(b32);
    const int slot  = __popc(b32 & ((1u << r) - 1u));

    float ux = 0.f, uy = 0.f, uz = 0.f;
    if (valid) {
        const float px = pos[3 * nj], py = pos[3 * nj + 1], pz = pos[3 * nj + 2];
        const float vx = px - cx, vy = py - cy, vz = pz - cz;
        const float d2 = fmaf(vx, vx, fmaf(vy, vy, vz * vz));
        const float inv = __builtin_amdgcn_rcpf(sqrtf(d2) + 1e-10f);
        ux = vx * inv; uy = vy * inv; uz = vz * inv;
    }

    // scatter: slot s's vector lands in lane (lbase+s); invalid lanes dump to
    // lane 31 of the group (slots are < 20, never read from lane 31).
    const int dst = (lbase + (valid ? slot : 31)) << 2;
    const float sx = __int_as_float(__builtin_amdgcn_ds_permute(dst, __float_as_int(ux)));
    const float sy = __int_as_float(__builtin_amdgcn_ds_permute(dst, __float_as_int(uy)));
    const float sz = __int_as_float(__builtin_amdgcn_ds_permute(dst, __float_as_int(uz)));

    const int npairs = (total * (total - 1)) >> 1;
    const int ntrips = (npairs + GRP - 1) >> 5;   // group-uniform trip count:
                                                  // keeps all 32 lanes active so
                                                  // bpermute sources are valid
    float gsum = 0.f, s2 = 0.f, s4 = 0.f, s6 = 0.f;
    int p = r;
    for (int t = 0; t < ntrips; ++t, p += GRP) {
        const int live = p < npairs;
        const int pc = live ? p : 0;              // decode a safe pair when dead
        // triangular decode (exact: 8p+1 is a perfect square at boundaries)
        const int j  = (int)((1.0f + sqrtf(fmaf(8.f, (float)pc, 1.0f))) * 0.5f);
        const int ii = pc - ((j * (j - 1)) >> 1);

        const int la = lbase + ii, lb = lbase + j;
        const float Ax = bperm(la, sx), Ay = bperm(la, sy), Az = bperm(la, sz);
        const float Bx = bperm(lb, sx), By = bperm(lb, sy), Bz = bperm(lb, sz);

        const float d = fmaf(Ax, Bx, fmaf(Ay, By, Az * Bz));
        const float w = (float)live;
        const float e = d * d;

        // Legendre sums for q2/q4/q6 (addition theorem)
        s2 = fmaf(w, fmaf(1.5f, e, -0.5f), s2);
        s4 = fmaf(w, fmaf(fmaf(4.375f, e, -3.75f), e, 0.375f), s4);
        s6 = fmaf(w, fmaf(fmaf(fmaf(14.4375f, e, -19.6875f), e, 6.5625f), e, -0.3125f), s6);

        // tetrahedral gaussian
        const float dc = fminf(fmaxf(d, -0.9999999f), 0.9999999f);
        const float ad = fabsf(dc);
        const float pq = fmaf(fmaf(fmaf(-0.0187293f, ad, 0.0742610f), ad, -0.2121144f), ad,
                              1.5707288f) * sqrtf(1.f - ad);
        const float ang = (dc >= 0.f) ? pq : PI_F - pq;
        const float tt = (ang - THETA_T) * INV_SIG;
        gsum = fmaf(w, __expf(-0.5f * tt * tt), gsum);
    }

#define RED(v) { v += __shfl_xor(v,1); v += __shfl_xor(v,2); v += __shfl_xor(v,4); \
                 v += __shfl_xor(v,8); v += __shfl_xor(v,16); }
    RED(gsum) RED(s2) RED(s4) RED(s6)
#undef RED

    const float cn = (float)total;
    const float invnb = 1.f / fmaxf(cn, 1.f);

    if      (r == 0) out[0 * M + i] = cn;
    else if (r == 1) out[1 * M + i] = 2.f * gsum / fmaxf(cn * (cn - 1.f), 1.f);
    else if (r == 2) out[2 * M + i] = invnb * sqrtf(fmaxf(fmaf(2.f, s2, cn), 0.f));
    else if (r == 3) out[3 * M + i] = invnb * sqrtf(fmaxf(fmaf(2.f, s4, cn), 0.f));
    else if (r == 4) out[4 * M + i] = invnb * sqrtf(fmaxf(fmaf(2.f, s6, cn), 0.f));
}

extern "C" void kernel_launch(void* const* d_in, const int* in_sizes, int n_in,
                              void* d_out, int out_size, void* d_ws, size_t ws_size,
                              hipStream_t stream) {
    const float* pos  = (const float*)d_in[0];
    const int*   aidx = (const int*)d_in[1];
    const int*   nidx = (const int*)d_in[2];
    const int*   vmsk = (const int*)d_in[3];
    float* out = (float*)d_out;
    const int M = in_sizes[1];
    const int grid = (M + APB - 1) / APB;
    op_kernel<<<grid, BLK, 0, stream>>>(pos, aidx, nidx, vmsk, out, M);
}